// Round 5
// baseline (376.471 us; speedup 1.0000x reference)
//
#include <hip/hip_runtime.h>
#include <math.h>

#define FIN 512
#define FH  64
#define FO  32

typedef __bf16 bf16_t;
typedef bf16_t bf16x8 __attribute__((ext_vector_type(8)));
typedef float  f32x4  __attribute__((ext_vector_type(4)));

__device__ __forceinline__ float bf_lo(unsigned u) {
  return __builtin_bit_cast(float, u << 16);
}
__device__ __forceinline__ float bf_hi(unsigned u) {
  return __builtin_bit_cast(float, u & 0xffff0000u);
}

// fused init: zero deg+cursor (2*NP ints), build W1T bf16 [64][512]
__global__ __launch_bounds__(256) void k_init(int* __restrict__ p, int n2,
                                              const float* __restrict__ W1,
                                              bf16_t* __restrict__ w1t) {
  int i = blockIdx.x * 256 + threadIdx.x;
  if (i < n2) p[i] = 0;
  if (i < FIN * FH) {  // write-contiguous W1T: c = i>>9, k = i&511
    int c = i >> 9, k = i & 511;
    w1t[i] = (bf16_t)W1[(size_t)k * FH + c];
  }
}

__global__ __launch_bounds__(256) void k_deg_hist(const int* __restrict__ dst,
                                                  int* __restrict__ deg, int E) {
  int i = blockIdx.x * 256 + threadIdx.x;
  if (i < E) atomicAdd(&deg[dst[i]], 1);
}

__global__ __launch_bounds__(256) void k_scan_block(const int* __restrict__ deg,
                                                    int* __restrict__ rowoff,
                                                    int* __restrict__ bsum,
                                                    float* __restrict__ dinv, int n) {
  __shared__ int s[256];
  int t = threadIdx.x;
  int i = blockIdx.x * 256 + t;
  int v = (i < n) ? deg[i] : 0;
  s[t] = v;
  __syncthreads();
  #pragma unroll
  for (int off = 1; off < 256; off <<= 1) {
    int tmp = (t >= off) ? s[t - off] : 0;
    __syncthreads();
    s[t] += tmp;
    __syncthreads();
  }
  if (i < n) {
    rowoff[i] = s[t] - v;
    dinv[i] = rsqrtf((float)(v + 1));
  }
  if (t == 255) bsum[blockIdx.x] = s[255];
}

__global__ __launch_bounds__(256) void k_scan_bsum(int* __restrict__ bsum, int nb) {
  __shared__ int s[256];
  int t = threadIdx.x;
  int carry = 0;
  for (int base = 0; base < nb; base += 256) {
    int idx = base + t;
    int v = (idx < nb) ? bsum[idx] : 0;
    s[t] = v;
    __syncthreads();
    #pragma unroll
    for (int off = 1; off < 256; off <<= 1) {
      int tmp = (t >= off) ? s[t - off] : 0;
      __syncthreads();
      s[t] += tmp;
      __syncthreads();
    }
    if (idx < nb) bsum[idx] = s[t] - v + carry;
    carry += s[255];
    __syncthreads();
  }
}

__global__ __launch_bounds__(256) void k_scan_add(int* __restrict__ rowoff,
                                                  const int* __restrict__ bsum, int n) {
  int i = blockIdx.x * 256 + threadIdx.x;
  if (i < n) rowoff[i] += bsum[blockIdx.x];
}

__global__ __launch_bounds__(256) void k_csr_fill(const int* __restrict__ ei,
                                                  const int* __restrict__ rowoff,
                                                  int* __restrict__ cursor,
                                                  int* __restrict__ csr, int E) {
  int e = blockIdx.x * 256 + threadIdx.x;
  if (e >= E) return;
  int s = ei[e];
  int d = ei[E + e];
  int pos = atomicAdd(&cursor[d], 1);
  csr[rowoff[d] + pos] = s;
}

// GEMM1 via MFMA: P1[n][64] (bf16) = dinv[n] * (x[n] @ W1). x-read-BW bound.
__global__ __launch_bounds__(256) void k_gemm1(const float* __restrict__ x,
                                               const bf16_t* __restrict__ w1t,
                                               const float* __restrict__ dinv,
                                               bf16_t* __restrict__ P1, int n) {
  int t = threadIdx.x;
  int w = t >> 6, l = t & 63;
  int rowBase = blockIdx.x * 64 + w * 16;
  int fr = l & 15, fk = l >> 4;
  int ar = rowBase + fr; if (ar >= n) ar = n - 1;
  const float* xp = x + (size_t)ar * FIN + fk * 8;
  const bf16_t* wb = w1t + (size_t)fr * FIN + fk * 8;

  f32x4 acc0 = {0.f, 0.f, 0.f, 0.f};
  f32x4 acc1 = {0.f, 0.f, 0.f, 0.f};
  f32x4 acc2 = {0.f, 0.f, 0.f, 0.f};
  f32x4 acc3 = {0.f, 0.f, 0.f, 0.f};

  #pragma unroll 4
  for (int kt = 0; kt < FIN; kt += 32) {
    float4 a0 = *(const float4*)(xp + kt);
    float4 a1 = *(const float4*)(xp + kt + 4);
    bf16x8 av;
    av[0] = (bf16_t)a0.x; av[1] = (bf16_t)a0.y; av[2] = (bf16_t)a0.z; av[3] = (bf16_t)a0.w;
    av[4] = (bf16_t)a1.x; av[5] = (bf16_t)a1.y; av[6] = (bf16_t)a1.z; av[7] = (bf16_t)a1.w;
    bf16x8 b0 = *(const bf16x8*)(wb + kt);
    bf16x8 b1 = *(const bf16x8*)(wb + (size_t)16 * FIN + kt);
    bf16x8 b2 = *(const bf16x8*)(wb + (size_t)32 * FIN + kt);
    bf16x8 b3 = *(const bf16x8*)(wb + (size_t)48 * FIN + kt);
    acc0 = __builtin_amdgcn_mfma_f32_16x16x32_bf16(av, b0, acc0, 0, 0, 0);
    acc1 = __builtin_amdgcn_mfma_f32_16x16x32_bf16(av, b1, acc1, 0, 0, 0);
    acc2 = __builtin_amdgcn_mfma_f32_16x16x32_bf16(av, b2, acc2, 0, 0, 0);
    acc3 = __builtin_amdgcn_mfma_f32_16x16x32_bf16(av, b3, acc3, 0, 0, 0);
  }

  #pragma unroll
  for (int rg = 0; rg < 4; rg++) {
    int grow = rowBase + fk * 4 + rg;
    if (grow < n) {
      float dv = dinv[grow];
      bf16_t* prow = P1 + (size_t)grow * FH + fr;
      prow[0]  = (bf16_t)(dv * acc0[rg]);
      prow[16] = (bf16_t)(dv * acc1[rg]);
      prow[32] = (bf16_t)(dv * acc2[rg]);
      prow[48] = (bf16_t)(dv * acc3[rg]);
    }
  }
}

// Fused gather1 + relu/bias + layer2 transform (h never materialized).
// Persistent waves; wave per node per iteration.
// Gather: 8 edge-slots (es=lane>>3) x 8 lanes (dg=lane&7) x bf16x8 (16B):
// avg-degree node has all ~16 edge rows in flight in one step.
// Then h (fp32, 8 dims/lane) -> P2[c] via 32 shfl+FMA against fp32 W2 regs.
__global__ __launch_bounds__(256) void k_g1g2(const bf16_t* __restrict__ P1,
                                              const int* __restrict__ csr,
                                              const int* __restrict__ rowoff,
                                              const int* __restrict__ deg,
                                              const float* __restrict__ dinv,
                                              const float* __restrict__ b1,
                                              const float* __restrict__ W2,
                                              bf16_t* __restrict__ P2, int n) {
  int l = threadIdx.x & 63;
  int es = l >> 3;       // edge slot 0..7
  int dg = l & 7;        // dim group: dims dg*8..dg*8+7
  int c = l & 31;        // output dim for gemm2
  int half = l >> 5;     // k-half for gemm2

  float w[32];
  #pragma unroll
  for (int i = 0; i < 32; i++) w[i] = W2[(size_t)(half * 32 + i) * FO + c];
  float4 bb0 = ((const float4*)b1)[dg * 2];
  float4 bb1 = ((const float4*)b1)[dg * 2 + 1];

  int gw = (blockIdx.x * 256 + threadIdx.x) >> 6;
  int nw = (gridDim.x * 256) >> 6;
  const uint4* P1v = (const uint4*)P1;

  for (int v = gw; v < n; v += nw) {
    int base = rowoff[v];
    int cnt = deg[v];
    float a0 = 0.f, a1 = 0.f, a2 = 0.f, a3 = 0.f, a4 = 0.f, a5 = 0.f, a6 = 0.f, a7 = 0.f;
    float c0 = 0.f, c1 = 0.f, c2 = 0.f, c3 = 0.f, c4 = 0.f, c5 = 0.f, c6 = 0.f, c7 = 0.f;
    if (es == 0) {  // self loop
      uint4 r = P1v[(size_t)v * 8 + dg];
      a0 += bf_lo(r.x); a1 += bf_hi(r.x); a2 += bf_lo(r.y); a3 += bf_hi(r.y);
      a4 += bf_lo(r.z); a5 += bf_hi(r.z); a6 += bf_lo(r.w); a7 += bf_hi(r.w);
    }
    int j = 0;
    for (; j + 16 <= cnt; j += 16) {
      int u0 = csr[base + j + es];
      int u1 = csr[base + j + 8 + es];
      uint4 r0 = P1v[(size_t)u0 * 8 + dg];
      uint4 r1 = P1v[(size_t)u1 * 8 + dg];
      a0 += bf_lo(r0.x); a1 += bf_hi(r0.x); a2 += bf_lo(r0.y); a3 += bf_hi(r0.y);
      a4 += bf_lo(r0.z); a5 += bf_hi(r0.z); a6 += bf_lo(r0.w); a7 += bf_hi(r0.w);
      c0 += bf_lo(r1.x); c1 += bf_hi(r1.x); c2 += bf_lo(r1.y); c3 += bf_hi(r1.y);
      c4 += bf_lo(r1.z); c5 += bf_hi(r1.z); c6 += bf_lo(r1.w); c7 += bf_hi(r1.w);
    }
    for (; j < cnt; j += 8) {
      if (j + es < cnt) {
        int u = csr[base + j + es];
        uint4 r = P1v[(size_t)u * 8 + dg];
        a0 += bf_lo(r.x); a1 += bf_hi(r.x); a2 += bf_lo(r.y); a3 += bf_hi(r.y);
        a4 += bf_lo(r.z); a5 += bf_hi(r.z); a6 += bf_lo(r.w); a7 += bf_hi(r.w);
      }
    }
    float h[8];
    h[0] = a0 + c0; h[1] = a1 + c1; h[2] = a2 + c2; h[3] = a3 + c3;
    h[4] = a4 + c4; h[5] = a5 + c5; h[6] = a6 + c6; h[7] = a7 + c7;
    #pragma unroll
    for (int off = 8; off <= 32; off <<= 1) {
      #pragma unroll
      for (int q = 0; q < 8; q++) h[q] += __shfl_xor(h[q], off, 64);
    }
    float dv = dinv[v];
    h[0] = fmaxf(dv * h[0] + bb0.x, 0.f);
    h[1] = fmaxf(dv * h[1] + bb0.y, 0.f);
    h[2] = fmaxf(dv * h[2] + bb0.z, 0.f);
    h[3] = fmaxf(dv * h[3] + bb0.w, 0.f);
    h[4] = fmaxf(dv * h[4] + bb1.x, 0.f);
    h[5] = fmaxf(dv * h[5] + bb1.y, 0.f);
    h[6] = fmaxf(dv * h[6] + bb1.z, 0.f);
    h[7] = fmaxf(dv * h[7] + bb1.w, 0.f);
    // gemm2: P2[c] = dv * sum_k h[k]*W2[k][c]; lane sums its 32-k half
    float s2 = 0.f;
    #pragma unroll
    for (int i = 0; i < 32; i++) {
      int src = (half << 2) + (i >> 3);
      s2 += __shfl(h[i & 7], src, 64) * w[i];
    }
    s2 += __shfl_xor(s2, 32, 64);
    if (l < 32) P2[(size_t)v * FO + c] = (bf16_t)(dv * s2);
  }
}

// gather2 + bias + log_softmax. Persistent waves; wave per node.
// 16 slots (es=lane>>2) x 4 lanes (dg=lane&3) x bf16x8: 16 rows in flight.
__global__ __launch_bounds__(256) void k_g2final(const bf16_t* __restrict__ P2,
                                                 const int* __restrict__ csr,
                                                 const int* __restrict__ rowoff,
                                                 const int* __restrict__ deg,
                                                 const float* __restrict__ dinv,
                                                 const float* __restrict__ b2,
                                                 float* __restrict__ out, int n) {
  int l = threadIdx.x & 63;
  int es = l >> 2;       // edge slot 0..15
  int dg = l & 3;        // dims dg*8..dg*8+7 of 32
  float4 bb0 = ((const float4*)b2)[dg * 2];
  float4 bb1 = ((const float4*)b2)[dg * 2 + 1];

  int gw = (blockIdx.x * 256 + threadIdx.x) >> 6;
  int nw = (gridDim.x * 256) >> 6;
  const uint4* P2v = (const uint4*)P2;

  for (int v = gw; v < n; v += nw) {
    int base = rowoff[v];
    int cnt = deg[v];
    float a0 = 0.f, a1 = 0.f, a2 = 0.f, a3 = 0.f, a4 = 0.f, a5 = 0.f, a6 = 0.f, a7 = 0.f;
    float c0 = 0.f, c1 = 0.f, c2 = 0.f, c3 = 0.f, c4 = 0.f, c5 = 0.f, c6 = 0.f, c7 = 0.f;
    if (es == 0) {  // self loop
      uint4 r = P2v[(size_t)v * 4 + dg];
      a0 += bf_lo(r.x); a1 += bf_hi(r.x); a2 += bf_lo(r.y); a3 += bf_hi(r.y);
      a4 += bf_lo(r.z); a5 += bf_hi(r.z); a6 += bf_lo(r.w); a7 += bf_hi(r.w);
    }
    int j = 0;
    for (; j + 32 <= cnt; j += 32) {
      int u0 = csr[base + j + es];
      int u1 = csr[base + j + 16 + es];
      uint4 r0 = P2v[(size_t)u0 * 4 + dg];
      uint4 r1 = P2v[(size_t)u1 * 4 + dg];
      a0 += bf_lo(r0.x); a1 += bf_hi(r0.x); a2 += bf_lo(r0.y); a3 += bf_hi(r0.y);
      a4 += bf_lo(r0.z); a5 += bf_hi(r0.z); a6 += bf_lo(r0.w); a7 += bf_hi(r0.w);
      c0 += bf_lo(r1.x); c1 += bf_hi(r1.x); c2 += bf_lo(r1.y); c3 += bf_hi(r1.y);
      c4 += bf_lo(r1.z); c5 += bf_hi(r1.z); c6 += bf_lo(r1.w); c7 += bf_hi(r1.w);
    }
    for (; j < cnt; j += 16) {
      if (j + es < cnt) {
        int u = csr[base + j + es];
        uint4 r = P2v[(size_t)u * 4 + dg];
        a0 += bf_lo(r.x); a1 += bf_hi(r.x); a2 += bf_lo(r.y); a3 += bf_hi(r.y);
        a4 += bf_lo(r.z); a5 += bf_hi(r.z); a6 += bf_lo(r.w); a7 += bf_hi(r.w);
      }
    }
    float s[8];
    s[0] = a0 + c0; s[1] = a1 + c1; s[2] = a2 + c2; s[3] = a3 + c3;
    s[4] = a4 + c4; s[5] = a5 + c5; s[6] = a6 + c6; s[7] = a7 + c7;
    #pragma unroll
    for (int off = 4; off <= 32; off <<= 1) {
      #pragma unroll
      for (int q = 0; q < 8; q++) s[q] += __shfl_xor(s[q], off, 64);
    }
    float dv = dinv[v];
    float val[8];
    val[0] = dv * s[0] + bb0.x; val[1] = dv * s[1] + bb0.y;
    val[2] = dv * s[2] + bb0.z; val[3] = dv * s[3] + bb0.w;
    val[4] = dv * s[4] + bb1.x; val[5] = dv * s[5] + bb1.y;
    val[6] = dv * s[6] + bb1.z; val[7] = dv * s[7] + bb1.w;
    float m = val[0];
    #pragma unroll
    for (int q = 1; q < 8; q++) m = fmaxf(m, val[q]);
    m = fmaxf(m, __shfl_xor(m, 1, 64));
    m = fmaxf(m, __shfl_xor(m, 2, 64));
    float se = 0.f;
    #pragma unroll
    for (int q = 0; q < 8; q++) se += expf(val[q] - m);
    se += __shfl_xor(se, 1, 64);
    se += __shfl_xor(se, 2, 64);
    float lse = m + logf(se);
    if (es == 0) {
      float4 o0, o1;
      o0.x = val[0] - lse; o0.y = val[1] - lse; o0.z = val[2] - lse; o0.w = val[3] - lse;
      o1.x = val[4] - lse; o1.y = val[5] - lse; o1.z = val[6] - lse; o1.w = val[7] - lse;
      float* orow = out + (size_t)v * FO + dg * 8;
      *(float4*)orow = o0;
      *(float4*)(orow + 4) = o1;
    }
  }
}

extern "C" void kernel_launch(void* const* d_in, const int* in_sizes, int n_in,
                              void* d_out, int out_size, void* d_ws, size_t ws_size,
                              hipStream_t stream) {
  const float* x  = (const float*)d_in[0];
  const int*   ei = (const int*)d_in[1];
  const float* W1 = (const float*)d_in[2];
  const float* b1 = (const float*)d_in[3];
  const float* W2 = (const float*)d_in[4];
  const float* b2 = (const float*)d_in[5];
  const int N = in_sizes[0] / FIN;
  const int E = in_sizes[1] / 2;
  float* out = (float*)d_out;

  size_t NP = ((size_t)N + 63) & ~(size_t)63;
  size_t EP = ((size_t)E + 63) & ~(size_t)63;
  int nb = (N + 255) / 256;

  int*    deg    = (int*)d_ws;             // NP
  int*    cursor = deg + NP;               // NP (contiguous with deg for zeroing)
  int*    rowoff = cursor + NP;            // NP
  int*    bsum   = rowoff + NP;            // 512
  float*  dinv   = (float*)(bsum + 512);   // NP
  int*    csr    = (int*)(dinv + NP);      // EP
  bf16_t* w1t    = (bf16_t*)(csr + EP);    // 64*512
  bf16_t* P1     = w1t + (size_t)FH * FIN; // NP*64
  bf16_t* P2     = P1 + NP * FH;           // NP*32

  int initN = (int)(2 * NP);
  if (initN < FIN * FH) initN = FIN * FH;
  k_init<<<(initN + 255) / 256, 256, 0, stream>>>(deg, (int)(2 * NP), W1, w1t);
  k_deg_hist<<<(E + 255) / 256, 256, 0, stream>>>(ei + E, deg, E);
  k_scan_block<<<nb, 256, 0, stream>>>(deg, rowoff, bsum, dinv, N);
  k_scan_bsum<<<1, 256, 0, stream>>>(bsum, nb);
  k_scan_add<<<nb, 256, 0, stream>>>(rowoff, bsum, N);
  k_csr_fill<<<(E + 255) / 256, 256, 0, stream>>>(ei, rowoff, cursor, csr, E);
  k_gemm1<<<(N + 63) / 64, 256, 0, stream>>>(x, w1t, dinv, P1, N);
  k_g1g2<<<2048, 256, 0, stream>>>(P1, csr, rowoff, deg, dinv, b1, W2, P2, N);
  k_g2final<<<2048, 256, 0, stream>>>(P2, csr, rowoff, deg, dinv, b2, out, N);
}

// Round 6
// 305.764 us; speedup vs baseline: 1.2312x; 1.2312x over previous
//
#include <hip/hip_runtime.h>
#include <math.h>

#define FIN 512
#define FH  64
#define FO  32

typedef __bf16 bf16_t;
typedef bf16_t bf16x8 __attribute__((ext_vector_type(8)));
typedef bf16_t bf16x4 __attribute__((ext_vector_type(4)));
typedef float  f32x4  __attribute__((ext_vector_type(4)));

__device__ __forceinline__ float bf_lo(unsigned u) {
  return __builtin_bit_cast(float, u << 16);
}
__device__ __forceinline__ float bf_hi(unsigned u) {
  return __builtin_bit_cast(float, u & 0xffff0000u);
}

// fused init: zero deg+cursor (2*NP ints), build W1T bf16 [64][512], W2T bf16 [32][64]
__global__ __launch_bounds__(256) void k_init(int* __restrict__ p, int n2,
                                              const float* __restrict__ W1,
                                              bf16_t* __restrict__ w1t,
                                              const float* __restrict__ W2,
                                              bf16_t* __restrict__ w2t) {
  int i = blockIdx.x * 256 + threadIdx.x;
  if (i < n2) p[i] = 0;
  if (i < FIN * FH) {
    int c = i >> 9, k = i & 511;
    w1t[i] = (bf16_t)W1[(size_t)k * FH + c];
  }
  if (i < FH * FO) {
    int c = i >> 6, k = i & 63;
    w2t[i] = (bf16_t)W2[(size_t)k * FO + c];
  }
}

__global__ __launch_bounds__(256) void k_deg_hist(const int* __restrict__ dst,
                                                  int* __restrict__ deg, int E) {
  int i = blockIdx.x * 256 + threadIdx.x;
  if (i < E) atomicAdd(&deg[dst[i]], 1);
}

__global__ __launch_bounds__(256) void k_scan_block(const int* __restrict__ deg,
                                                    int* __restrict__ rowoff,
                                                    int* __restrict__ bsum,
                                                    float* __restrict__ dinv, int n) {
  __shared__ int s[256];
  int t = threadIdx.x;
  int i = blockIdx.x * 256 + t;
  int v = (i < n) ? deg[i] : 0;
  s[t] = v;
  __syncthreads();
  #pragma unroll
  for (int off = 1; off < 256; off <<= 1) {
    int tmp = (t >= off) ? s[t - off] : 0;
    __syncthreads();
    s[t] += tmp;
    __syncthreads();
  }
  if (i < n) {
    rowoff[i] = s[t] - v;
    dinv[i] = rsqrtf((float)(v + 1));
  }
  if (t == 255) bsum[blockIdx.x] = s[255];
}

__global__ __launch_bounds__(256) void k_scan_bsum(int* __restrict__ bsum, int nb) {
  __shared__ int s[256];
  int t = threadIdx.x;
  int carry = 0;
  for (int base = 0; base < nb; base += 256) {
    int idx = base + t;
    int v = (idx < nb) ? bsum[idx] : 0;
    s[t] = v;
    __syncthreads();
    #pragma unroll
    for (int off = 1; off < 256; off <<= 1) {
      int tmp = (t >= off) ? s[t - off] : 0;
      __syncthreads();
      s[t] += tmp;
      __syncthreads();
    }
    if (idx < nb) bsum[idx] = s[t] - v + carry;
    carry += s[255];
    __syncthreads();
  }
}

__global__ __launch_bounds__(256) void k_scan_add(int* __restrict__ rowoff,
                                                  const int* __restrict__ bsum, int n) {
  int i = blockIdx.x * 256 + threadIdx.x;
  if (i < n) rowoff[i] += bsum[blockIdx.x];
}

__global__ __launch_bounds__(256) void k_csr_fill(const int* __restrict__ ei,
                                                  const int* __restrict__ rowoff,
                                                  int* __restrict__ cursor,
                                                  int* __restrict__ csr, int E) {
  int e = blockIdx.x * 256 + threadIdx.x;
  if (e >= E) return;
  int s = ei[e];
  int d = ei[E + e];
  int pos = atomicAdd(&cursor[d], 1);
  csr[rowoff[d] + pos] = s;
}

// GEMM1 via MFMA: P1[n][64] (bf16) = dinv[n] * (x[n] @ W1). x-read-BW bound.
__global__ __launch_bounds__(256) void k_gemm1(const float* __restrict__ x,
                                               const bf16_t* __restrict__ w1t,
                                               const float* __restrict__ dinv,
                                               bf16_t* __restrict__ P1, int n) {
  int t = threadIdx.x;
  int w = t >> 6, l = t & 63;
  int rowBase = blockIdx.x * 64 + w * 16;
  int fr = l & 15, fk = l >> 4;
  int ar = rowBase + fr; if (ar >= n) ar = n - 1;
  const float* xp = x + (size_t)ar * FIN + fk * 8;
  const bf16_t* wb = w1t + (size_t)fr * FIN + fk * 8;

  f32x4 acc0 = {0.f, 0.f, 0.f, 0.f};
  f32x4 acc1 = {0.f, 0.f, 0.f, 0.f};
  f32x4 acc2 = {0.f, 0.f, 0.f, 0.f};
  f32x4 acc3 = {0.f, 0.f, 0.f, 0.f};

  #pragma unroll 4
  for (int kt = 0; kt < FIN; kt += 32) {
    float4 a0 = *(const float4*)(xp + kt);
    float4 a1 = *(const float4*)(xp + kt + 4);
    bf16x8 av;
    av[0] = (bf16_t)a0.x; av[1] = (bf16_t)a0.y; av[2] = (bf16_t)a0.z; av[3] = (bf16_t)a0.w;
    av[4] = (bf16_t)a1.x; av[5] = (bf16_t)a1.y; av[6] = (bf16_t)a1.z; av[7] = (bf16_t)a1.w;
    bf16x8 b0 = *(const bf16x8*)(wb + kt);
    bf16x8 b1 = *(const bf16x8*)(wb + (size_t)16 * FIN + kt);
    bf16x8 b2 = *(const bf16x8*)(wb + (size_t)32 * FIN + kt);
    bf16x8 b3 = *(const bf16x8*)(wb + (size_t)48 * FIN + kt);
    acc0 = __builtin_amdgcn_mfma_f32_16x16x32_bf16(av, b0, acc0, 0, 0, 0);
    acc1 = __builtin_amdgcn_mfma_f32_16x16x32_bf16(av, b1, acc1, 0, 0, 0);
    acc2 = __builtin_amdgcn_mfma_f32_16x16x32_bf16(av, b2, acc2, 0, 0, 0);
    acc3 = __builtin_amdgcn_mfma_f32_16x16x32_bf16(av, b3, acc3, 0, 0, 0);
  }

  #pragma unroll
  for (int rg = 0; rg < 4; rg++) {
    int grow = rowBase + fk * 4 + rg;
    if (grow < n) {
      float dv = dinv[grow];
      bf16_t* prow = P1 + (size_t)grow * FH + fr;
      prow[0]  = (bf16_t)(dv * acc0[rg]);
      prow[16] = (bf16_t)(dv * acc1[rg]);
      prow[32] = (bf16_t)(dv * acc2[rg]);
      prow[48] = (bf16_t)(dv * acc3[rg]);
    }
  }
}

// gather1: wave = 4 independent 16-lane subgroups, one NODE each.
// 16 lanes x uint2(8B) cover the 128B P1 row. Serial 4-unrolled edge walk:
// 4 rows in flight per subgroup (16/wave), zero shfl, zero slot waste.
// Epilogue fused: h = relu(dinv*sum + b1) -> bf16.
__global__ __launch_bounds__(256) void k_gather1(const bf16_t* __restrict__ P1,
                                                 const int* __restrict__ csr,
                                                 const int* __restrict__ rowoff,
                                                 const int* __restrict__ deg,
                                                 const float* __restrict__ dinv,
                                                 const float* __restrict__ b1,
                                                 bf16_t* __restrict__ h, int n) {
  int l = threadIdx.x & 63;
  int g = l >> 4, dg = l & 15;
  int wv = (blockIdx.x * 256 + threadIdx.x) >> 6;
  int v = wv * 4 + g;
  if (v >= n) return;
  const uint2* P1v = (const uint2*)P1;
  int base = rowoff[v];
  int cnt = deg[v];
  uint2 sv = P1v[(size_t)v * 16 + dg];  // self loop
  float a0 = bf_lo(sv.x), a1 = bf_hi(sv.x), a2 = bf_lo(sv.y), a3 = bf_hi(sv.y);
  float c0 = 0.f, c1 = 0.f, c2 = 0.f, c3 = 0.f;
  int cnt4 = cnt & ~3;
  int j = 0;
  for (; j < cnt4; j += 4) {
    int u0 = csr[base + j];
    int u1 = csr[base + j + 1];
    int u2 = csr[base + j + 2];
    int u3 = csr[base + j + 3];
    uint2 r0 = P1v[(size_t)u0 * 16 + dg];
    uint2 r1 = P1v[(size_t)u1 * 16 + dg];
    uint2 r2 = P1v[(size_t)u2 * 16 + dg];
    uint2 r3 = P1v[(size_t)u3 * 16 + dg];
    a0 += bf_lo(r0.x); a1 += bf_hi(r0.x); a2 += bf_lo(r0.y); a3 += bf_hi(r0.y);
    c0 += bf_lo(r1.x); c1 += bf_hi(r1.x); c2 += bf_lo(r1.y); c3 += bf_hi(r1.y);
    a0 += bf_lo(r2.x); a1 += bf_hi(r2.x); a2 += bf_lo(r2.y); a3 += bf_hi(r2.y);
    c0 += bf_lo(r3.x); c1 += bf_hi(r3.x); c2 += bf_lo(r3.y); c3 += bf_hi(r3.y);
  }
  for (; j < cnt; j++) {
    int u = csr[base + j];
    uint2 r = P1v[(size_t)u * 16 + dg];
    a0 += bf_lo(r.x); a1 += bf_hi(r.x); a2 += bf_lo(r.y); a3 += bf_hi(r.y);
  }
  a0 += c0; a1 += c1; a2 += c2; a3 += c3;
  float dv = dinv[v];
  float4 bb = ((const float4*)b1)[dg];
  bf16x4 hv;
  hv[0] = (bf16_t)fmaxf(dv * a0 + bb.x, 0.f);
  hv[1] = (bf16_t)fmaxf(dv * a1 + bb.y, 0.f);
  hv[2] = (bf16_t)fmaxf(dv * a2 + bb.z, 0.f);
  hv[3] = (bf16_t)fmaxf(dv * a3 + bb.w, 0.f);
  ((bf16x4*)h)[(size_t)v * 16 + dg] = hv;
}

// GEMM2 via MFMA: P2[n][32] (bf16) = dinv[n] * (h[n] @ W2)
__global__ __launch_bounds__(256) void k_gemm2(const bf16_t* __restrict__ h,
                                               const bf16_t* __restrict__ w2t,
                                               const float* __restrict__ dinv,
                                               bf16_t* __restrict__ P2, int n) {
  int t = threadIdx.x;
  int w = t >> 6, l = t & 63;
  int rowBase = blockIdx.x * 64 + w * 16;
  int fr = l & 15, fk = l >> 4;
  int ar = rowBase + fr; if (ar >= n) ar = n - 1;
  const bf16_t* hp = h + (size_t)ar * FH + fk * 8;
  const bf16_t* wb0 = w2t + (size_t)fr * FH + fk * 8;
  const bf16_t* wb1 = w2t + (size_t)(fr + 16) * FH + fk * 8;

  f32x4 acc0 = {0.f, 0.f, 0.f, 0.f};
  f32x4 acc1 = {0.f, 0.f, 0.f, 0.f};
  #pragma unroll
  for (int kt = 0; kt < FH; kt += 32) {
    bf16x8 af = *(const bf16x8*)(hp + kt);
    bf16x8 b0 = *(const bf16x8*)(wb0 + kt);
    bf16x8 b1 = *(const bf16x8*)(wb1 + kt);
    acc0 = __builtin_amdgcn_mfma_f32_16x16x32_bf16(af, b0, acc0, 0, 0, 0);
    acc1 = __builtin_amdgcn_mfma_f32_16x16x32_bf16(af, b1, acc1, 0, 0, 0);
  }
  #pragma unroll
  for (int rg = 0; rg < 4; rg++) {
    int grow = rowBase + fk * 4 + rg;
    if (grow < n) {
      float dv = dinv[grow];
      P2[(size_t)grow * FO + fr]      = (bf16_t)(dv * acc0[rg]);
      P2[(size_t)grow * FO + fr + 16] = (bf16_t)(dv * acc1[rg]);
    }
  }
}

// gather2 + bias + log_softmax: wave = 8 subgroups x 8 lanes, one node each.
// 8 lanes x uint2(8B) cover the 64B P2 row. shfl_xor(1,2,4) stays in-group.
__global__ __launch_bounds__(256) void k_g2final(const bf16_t* __restrict__ P2,
                                                 const int* __restrict__ csr,
                                                 const int* __restrict__ rowoff,
                                                 const int* __restrict__ deg,
                                                 const float* __restrict__ dinv,
                                                 const float* __restrict__ b2,
                                                 float* __restrict__ out, int n) {
  int l = threadIdx.x & 63;
  int g = l >> 3, dg = l & 7;
  int wv = (blockIdx.x * 256 + threadIdx.x) >> 6;
  int v = wv * 8 + g;
  if (v >= n) return;
  const uint2* P2v = (const uint2*)P2;
  int base = rowoff[v];
  int cnt = deg[v];
  uint2 sv = P2v[(size_t)v * 8 + dg];  // self loop
  float a0 = bf_lo(sv.x), a1 = bf_hi(sv.x), a2 = bf_lo(sv.y), a3 = bf_hi(sv.y);
  float c0 = 0.f, c1 = 0.f, c2 = 0.f, c3 = 0.f;
  int cnt4 = cnt & ~3;
  int j = 0;
  for (; j < cnt4; j += 4) {
    int u0 = csr[base + j];
    int u1 = csr[base + j + 1];
    int u2 = csr[base + j + 2];
    int u3 = csr[base + j + 3];
    uint2 r0 = P2v[(size_t)u0 * 8 + dg];
    uint2 r1 = P2v[(size_t)u1 * 8 + dg];
    uint2 r2 = P2v[(size_t)u2 * 8 + dg];
    uint2 r3 = P2v[(size_t)u3 * 8 + dg];
    a0 += bf_lo(r0.x); a1 += bf_hi(r0.x); a2 += bf_lo(r0.y); a3 += bf_hi(r0.y);
    c0 += bf_lo(r1.x); c1 += bf_hi(r1.x); c2 += bf_lo(r1.y); c3 += bf_hi(r1.y);
    a0 += bf_lo(r2.x); a1 += bf_hi(r2.x); a2 += bf_lo(r2.y); a3 += bf_hi(r2.y);
    c0 += bf_lo(r3.x); c1 += bf_hi(r3.x); c2 += bf_lo(r3.y); c3 += bf_hi(r3.y);
  }
  for (; j < cnt; j++) {
    int u = csr[base + j];
    uint2 r = P2v[(size_t)u * 8 + dg];
    a0 += bf_lo(r.x); a1 += bf_hi(r.x); a2 += bf_lo(r.y); a3 += bf_hi(r.y);
  }
  a0 += c0; a1 += c1; a2 += c2; a3 += c3;
  float dv = dinv[v];
  float4 bb = ((const float4*)b2)[dg & 7];
  float v0 = dv * a0 + bb.x;
  float v1 = dv * a1 + bb.y;
  float v2 = dv * a2 + bb.z;
  float v3 = dv * a3 + bb.w;
  float m = fmaxf(fmaxf(v0, v1), fmaxf(v2, v3));
  m = fmaxf(m, __shfl_xor(m, 1, 64));
  m = fmaxf(m, __shfl_xor(m, 2, 64));
  m = fmaxf(m, __shfl_xor(m, 4, 64));
  float se = expf(v0 - m) + expf(v1 - m) + expf(v2 - m) + expf(v3 - m);
  se += __shfl_xor(se, 1, 64);
  se += __shfl_xor(se, 2, 64);
  se += __shfl_xor(se, 4, 64);
  float lse = m + logf(se);
  float4 o;
  o.x = v0 - lse; o.y = v1 - lse; o.z = v2 - lse; o.w = v3 - lse;
  *(float4*)(out + (size_t)v * FO + dg * 4) = o;
}

extern "C" void kernel_launch(void* const* d_in, const int* in_sizes, int n_in,
                              void* d_out, int out_size, void* d_ws, size_t ws_size,
                              hipStream_t stream) {
  const float* x  = (const float*)d_in[0];
  const int*   ei = (const int*)d_in[1];
  const float* W1 = (const float*)d_in[2];
  const float* b1 = (const float*)d_in[3];
  const float* W2 = (const float*)d_in[4];
  const float* b2 = (const float*)d_in[5];
  const int N = in_sizes[0] / FIN;
  const int E = in_sizes[1] / 2;
  float* out = (float*)d_out;

  size_t NP = ((size_t)N + 63) & ~(size_t)63;
  size_t EP = ((size_t)E + 63) & ~(size_t)63;
  int nb = (N + 255) / 256;

  int*    deg    = (int*)d_ws;             // NP
  int*    cursor = deg + NP;               // NP (contiguous with deg for zeroing)
  int*    rowoff = cursor + NP;            // NP
  int*    bsum   = rowoff + NP;            // 512
  float*  dinv   = (float*)(bsum + 512);   // NP
  int*    csr    = (int*)(dinv + NP);      // EP
  bf16_t* w1t    = (bf16_t*)(csr + EP);    // 64*512
  bf16_t* w2t    = w1t + (size_t)FH * FIN; // 32*64
  bf16_t* P1     = w2t + (size_t)FO * FH;  // NP*64
  bf16_t* h      = P1 + NP * FH;           // NP*64
  bf16_t* P2     = h + NP * FH;            // NP*32

  int initN = (int)(2 * NP);
  if (initN < FIN * FH) initN = FIN * FH;
  k_init<<<(initN + 255) / 256, 256, 0, stream>>>(deg, (int)(2 * NP), W1, w1t, W2, w2t);
  k_deg_hist<<<(E + 255) / 256, 256, 0, stream>>>(ei + E, deg, E);
  k_scan_block<<<nb, 256, 0, stream>>>(deg, rowoff, bsum, dinv, N);
  k_scan_bsum<<<1, 256, 0, stream>>>(bsum, nb);
  k_scan_add<<<nb, 256, 0, stream>>>(rowoff, bsum, N);
  k_csr_fill<<<(E + 255) / 256, 256, 0, stream>>>(ei, rowoff, cursor, csr, E);
  k_gemm1<<<(N + 63) / 64, 256, 0, stream>>>(x, w1t, dinv, P1, N);
  {
    int waves = (N + 3) / 4;
    k_gather1<<<(waves + 3) / 4, 256, 0, stream>>>(P1, csr, rowoff, deg, dinv, b1, h, N);
  }
  k_gemm2<<<(N + 63) / 64, 256, 0, stream>>>(h, w2t, dinv, P2, N);
  {
    int waves = (N + 7) / 8;
    k_g2final<<<(waves + 3) / 4, 256, 0, stream>>>(P2, csr, rowoff, deg, dinv, b2, out, N);
  }
}